// Round 12
// baseline (252.568 us; speedup 1.0000x reference)
//
#include <hip/hip_runtime.h>
#include <math.h>

#define N_NODES 100000
#define BSHIFT 9                 // 512-node buckets
#define NBUCK 256                // >= ceil(N/512)=196, pow2
#define CAPSHIFT 13              // 8192 slots per bucket (mean 6122, +26 sigma)
#define CAP (1 << CAPSHIFT)

typedef unsigned short bfu;
typedef unsigned int uint;
typedef __attribute__((ext_vector_type(8))) short short8v;   // 8 bf16 = 4 VGPRs
typedef __attribute__((ext_vector_type(4))) float f32x4;
typedef __attribute__((ext_vector_type(2))) float f32x2;

__device__ __forceinline__ float bf2f(bfu u) {
    union { uint i; float f; } v; v.i = (uint)u << 16; return v.f;
}
__device__ __forceinline__ bfu f2bf(float f) {   // round-to-nearest-even
    union { float f_; uint i; } v; v.f_ = f;
    uint r = (v.i + 0x7FFFu + ((v.i >> 16) & 1u)) >> 16;
    return (bfu)r;
}
__device__ __forceinline__ float asf(uint u) {
    union { uint i; float f; } v; v.i = u; return v.f;
}

// ---------------------------------------------------------------- P1: bin edges by bucket
// Static bucket bases (b*CAP); per-chunk reservation via gcursor atomics.
__global__ __launch_bounds__(256) void bin_edges(const int* __restrict__ src,
                                                 const int* __restrict__ dst,
                                                 int* __restrict__ gcursor,
                                                 uint* __restrict__ binned, int nE) {
    __shared__ int h[NBUCK];
    __shared__ int base[NBUCK];
    int tid = threadIdx.x;
    int start = blockIdx.x * 4096;
    h[tid] = 0;
    __syncthreads();
    int bkt[16], rnk[16];
    #pragma unroll
    for (int u = 0; u < 16; ++u) {
        int e = start + u * 256 + tid;
        bkt[u] = -1;
        if (e < nE) {
            int b = dst[e] >> BSHIFT;
            bkt[u] = b;
            rnk[u] = atomicAdd(&h[b], 1);
        }
    }
    __syncthreads();
    base[tid] = h[tid] ? (tid << CAPSHIFT) + atomicAdd(&gcursor[tid], h[tid]) : 0;
    __syncthreads();
    #pragma unroll
    for (int u = 0; u < 16; ++u) {
        int e = start + u * 256 + tid;
        if (e < nE) {
            uint pk = ((uint)(dst[e] & 511) << 17) | (uint)src[e];  // src < 2^17
            binned[base[bkt[u]] + rnk[u]] = pk;
        }
    }
}

// ---------------------------------------------------------------- P2: per-bucket CSR build
// Gapped bucket-major nbr; rowptr/rowend per node; z0 panel-layout epilogue.
__global__ __launch_bounds__(512) void build_csr(
    const uint* __restrict__ binned, const int* __restrict__ gcursor,
    int* __restrict__ rowptr, int* __restrict__ rowend,
    float* __restrict__ dinv, int* __restrict__ nbr,
    const float4* __restrict__ x, bfu* __restrict__ z0, int nN) {
    __shared__ int hist[512];
    __shared__ int cursor[512];
    int b = blockIdx.x, t = threadIdx.x;
    int n0 = b << BSHIFT;
    int nNodes = min(512, nN - n0);
    int base = b << CAPSHIFT;
    int cnt = gcursor[b];
    hist[t] = 0;
    __syncthreads();
    for (int i = t; i < cnt; i += 512)
        atomicAdd(&hist[binned[base + i] >> 17], 1);
    __syncthreads();
    int v = hist[t];
    #pragma unroll
    for (int off = 1; off < 512; off <<= 1) {
        int tv = (t >= off) ? hist[t - off] : 0;
        __syncthreads();
        hist[t] += tv;
        __syncthreads();
    }
    int excl = hist[t] - v;
    float dv = rsqrtf((float)v + 1.0f);           // +1 self loop
    if (t < nNodes) {
        rowptr[n0 + t] = base + excl;
        rowend[n0 + t] = base + excl + v;
        dinv[n0 + t] = dv;
    }
    cursor[t] = excl;
    __syncthreads();
    ((float*)hist)[t] = dv;                        // hist reused as dinv cache
    __syncthreads();
    for (int i = t; i < cnt; i += 512) {
        uint pk = binned[base + i];
        int ld = pk >> 17;
        int pos = atomicAdd(&cursor[ld], 1);
        nbr[base + pos] = (int)(pk & 0x1FFFFu);
    }
    // epilogue: z0 = bf16(dinv*x) in PANEL layout [panel][node][16]
    const float4* xr = x + (size_t)n0 * 16;
    int totalF4 = nNodes * 16;
    for (int i = t; i < totalF4; i += 512) {
        int n = i >> 4, f4 = i & 15;              // f4: which 4-feat group
        float w = ((float*)hist)[n];
        float4 vv = xr[i];
        ushort4 o;
        o.x = f2bf(w * vv.x); o.y = f2bf(w * vv.y);
        o.z = f2bf(w * vv.z); o.w = f2bf(w * vv.w);
        *(ushort4*)(z0 + ((size_t)(f4 >> 2)) * nN * 16
                       + (size_t)(n0 + n) * 16 + (f4 & 3) * 4) = o;
    }
}

// ---------------------------------------------------------------- panel gather hop
// Feature-panel layout: z[panel][node][16 feats]. Block -> (XCD slot b&7) ->
// panel (b&7)>>1: each XCD touches ONE 3.2MB panel (L2-resident). Wave = 16
// edge-slots x 4 lanes (8B = 4 feats per lane); 16 nodes per wave.
template<int PW>
__global__ __launch_bounds__(256, 8) void gather_panel(
    bfu* __restrict__ out, const bfu* __restrict__ z,
    const int* __restrict__ nbr, const int* __restrict__ rowptr,
    const int* __restrict__ rowend, const float* __restrict__ dinv, int nN) {
    int b = blockIdx.x;
    int panel = (b & 7) >> 1;
    int chunk = ((b >> 3) << 1) | (b & 1);
    int wv = threadIdx.x >> 6, lane = threadIdx.x & 63;
    int e = lane >> 2, q = lane & 3;              // edge-slot, quarter-row
    const bfu* zp = z + (size_t)panel * nN * 16;
    bfu* op = out + (size_t)panel * nN * 16;
    int node0 = chunk * 64 + wv * 16;

    for (int m = 0; m < 16; ++m) {
        int node = node0 + m;
        if (node >= nN) return;
        int beg = rowptr[node], end = rowend[node];
        f32x2 lo = {0.f, 0.f}, hi = {0.f, 0.f};
        auto accum = [&](uint2 v) {
            f32x2 p;
            p.x = asf(v.x << 16); p.y = asf(v.x & 0xFFFF0000u); lo += p;
            p.x = asf(v.y << 16); p.y = asf(v.y & 0xFFFF0000u); hi += p;
        };
        if (e == 0)   // self loop
            accum(*(const uint2*)(zp + (size_t)node * 16 + q * 4));
        for (int j = beg + e; j < end; j += 16)
            accum(*(const uint2*)(zp + (size_t)nbr[j] * 16 + q * 4));

        float a[4] = {lo.x, lo.y, hi.x, hi.y};
        #pragma unroll
        for (int msk = 4; msk < 64; msk <<= 1)
            #pragma unroll
            for (int i = 0; i < 4; ++i)
                a[i] += __shfl_xor(a[i], msk);

        if (e == 0) {
            float di = dinv[node];
            float w = (PW == 2) ? di * di : di;
            ushort4 o;
            o.x = f2bf(a[0] * w); o.y = f2bf(a[1] * w);
            o.z = f2bf(a[2] * w); o.w = f2bf(a[3] * w);
            *(ushort4*)(op + (size_t)node * 16 + q * 4) = o;
        }
    }
}

// ---------------------------------------------------------------- MFMA MLP + log_softmax
// PERSISTENT: stages weights once, grid-strides over 64-node tiles.
// A-fragments read from panel layout: feats kg*8.. = panel kg>>1, half kg&1.
__global__ __launch_bounds__(256) void mlp_mfma(
    float* __restrict__ out, const bfu* __restrict__ zC,
    const float* __restrict__ W1, const float* __restrict__ b1,
    const float* __restrict__ W2, const float* __restrict__ b2,
    int nN, int nTiles) {
    __shared__ short w1t[64 * 72];   // w1t[n][k] bf16
    __shared__ short w2t[48 * 72];   // w2t[n][k] bf16, n 40..47 = 0
    __shared__ short hlds[64 * 72];  // h[node][hid] bf16
    __shared__ float b1s[64];
    __shared__ float b2s[48];

    int tid = threadIdx.x;
    for (int i = tid; i < 64 * 64; i += 256) {
        int k = i >> 6, n = i & 63;
        w1t[n * 72 + k] = (short)f2bf(W1[i]);
    }
    for (int i = tid; i < 48 * 64; i += 256) {
        int k = i / 48, n = i % 48;
        w2t[n * 72 + k] = (short)(n < 40 ? f2bf(W2[k * 40 + n]) : 0);
    }
    if (tid < 64) b1s[tid] = b1[tid];
    if (tid >= 64 && tid < 112) b2s[tid - 64] = (tid - 64 < 40) ? b2[tid - 64] : 0.f;

    int wv = tid >> 6, l = tid & 63;
    int li = l & 15, kg = l >> 4;

    for (int tile = blockIdx.x; tile < nTiles; tile += gridDim.x) {
        int nodebase = tile * 64 + wv * 16;
        int nclamp = min(nodebase + li, nN - 1);

        // A frags from panels: feats kg*8 -> panel kg>>1 half kg&1; +32 -> +2 panels
        short8v a0 = *(const short8v*)(zC + ((size_t)(kg >> 1)) * nN * 16
                                          + (size_t)nclamp * 16 + (kg & 1) * 8);
        short8v a1 = *(const short8v*)(zC + ((size_t)(2 + (kg >> 1))) * nN * 16
                                          + (size_t)nclamp * 16 + (kg & 1) * 8);
        __syncthreads();   // weights staged (iter 0); hlds readers done (iter >0)

        f32x4 acc[4];
        #pragma unroll
        for (int nt = 0; nt < 4; ++nt) {
            f32x4 c = {0.f, 0.f, 0.f, 0.f};
            short8v b0 = *(const short8v*)&w1t[(nt * 16 + li) * 72 + kg * 8];
            short8v b1f = *(const short8v*)&w1t[(nt * 16 + li) * 72 + 32 + kg * 8];
            c = __builtin_amdgcn_mfma_f32_16x16x32_bf16(a0, b0, c, 0, 0, 0);
            c = __builtin_amdgcn_mfma_f32_16x16x32_bf16(a1, b1f, c, 0, 0, 0);
            acc[nt] = c;
        }
        #pragma unroll
        for (int nt = 0; nt < 4; ++nt) {
            float bb = b1s[nt * 16 + li];
            #pragma unroll
            for (int r = 0; r < 4; ++r) {
                float v = fmaxf(acc[nt][r] + bb, 0.f);
                hlds[(wv * 16 + kg * 4 + r) * 72 + nt * 16 + li] = (short)f2bf(v);
            }
        }
        __syncthreads();

        const short8v* hp = (const short8v*)&hlds[(wv * 16 + li) * 72];
        short8v ha0 = hp[kg];
        short8v ha1 = hp[kg + 4];
        f32x4 acc2[3];
        #pragma unroll
        for (int nt = 0; nt < 3; ++nt) {
            f32x4 c = {0.f, 0.f, 0.f, 0.f};
            short8v b0 = *(const short8v*)&w2t[(nt * 16 + li) * 72 + kg * 8];
            short8v b1f = *(const short8v*)&w2t[(nt * 16 + li) * 72 + 32 + kg * 8];
            c = __builtin_amdgcn_mfma_f32_16x16x32_bf16(ha0, b0, c, 0, 0, 0);
            c = __builtin_amdgcn_mfma_f32_16x16x32_bf16(ha1, b1f, c, 0, 0, 0);
            acc2[nt] = c;
        }

        float lg[3][4];
        #pragma unroll
        for (int nt = 0; nt < 3; ++nt) {
            float bb = b2s[nt * 16 + li];
            #pragma unroll
            for (int r = 0; r < 4; ++r) lg[nt][r] = acc2[nt][r] + bb;
        }
        bool v2 = (li < 8);   // tile 2 valid cols 32..39
        float mx[4], sm[4];
        #pragma unroll
        for (int r = 0; r < 4; ++r) {
            float m = fmaxf(lg[0][r], lg[1][r]);
            if (v2) m = fmaxf(m, lg[2][r]);
            mx[r] = m;
        }
        #pragma unroll
        for (int off = 1; off < 16; off <<= 1)
            #pragma unroll
            for (int r = 0; r < 4; ++r)
                mx[r] = fmaxf(mx[r], __shfl_xor(mx[r], off));
        #pragma unroll
        for (int r = 0; r < 4; ++r) {
            float s = expf(lg[0][r] - mx[r]) + expf(lg[1][r] - mx[r]);
            if (v2) s += expf(lg[2][r] - mx[r]);
            sm[r] = s;
        }
        #pragma unroll
        for (int off = 1; off < 16; off <<= 1)
            #pragma unroll
            for (int r = 0; r < 4; ++r)
                sm[r] += __shfl_xor(sm[r], off);

        int nb2 = nodebase + kg * 4;
        #pragma unroll
        for (int r = 0; r < 4; ++r) {
            int nd = nb2 + r;
            if (nd < nN) {
                float lse = mx[r] + logf(sm[r]);
                out[(size_t)nd * 40 + li]      = lg[0][r] - lse;
                out[(size_t)nd * 40 + 16 + li] = lg[1][r] - lse;
                if (v2) out[(size_t)nd * 40 + 32 + li] = lg[2][r] - lse;
            }
        }
    }
}

extern "C" void kernel_launch(void* const* d_in, const int* in_sizes, int n_in,
                              void* d_out, int out_size, void* d_ws, size_t ws_size,
                              hipStream_t stream) {
    const float* x   = (const float*)d_in[0];
    const int* eidx  = (const int*)d_in[1];
    const float* W1  = (const float*)d_in[2];
    const float* b1  = (const float*)d_in[3];
    const float* W2  = (const float*)d_in[4];
    const float* b2  = (const float*)d_in[5];
    float* out = (float*)d_out;

    const int nN = N_NODES;
    const int nE = in_sizes[1] / 2;  // edge_index is [2, E]
    const int* src = eidx;
    const int* dst = eidx + nE;
    const int nBk = (nN + 511) >> BSHIFT;   // 196 buckets

    // ---- workspace layout (256B aligned)
    char* ws = (char*)d_ws;
    size_t off = 0;
    auto alloc = [&](size_t bytes) {
        char* p = ws + off;
        off += (bytes + 255) & ~(size_t)255;
        return p;
    };
    float* dinv    = (float*)alloc((size_t)nN * 4);
    int*   gcursor = (int*)  alloc(NBUCK * 4);
    int*   rowptr  = (int*)  alloc((size_t)nN * 4);
    int*   rowend  = (int*)  alloc((size_t)nN * 4);
    uint*  binned  = (uint*) alloc((size_t)NBUCK * CAP * 4);   // 8 MB, gapped
    int*   nbr     = (int*)  alloc((size_t)NBUCK * CAP * 4);   // 8 MB, gapped
    bfu*   z0      = (bfu*)  alloc((size_t)nN * 64 * 2);       // panel layout
    bfu*   zB      = (bfu*)  alloc((size_t)nN * 64 * 2);       // panel layout
    bfu*   zC      = (bfu*)  alloc((size_t)nN * 64 * 2);       // panel layout

    // 1. CSR build: bin (static bucket bases) -> per-bucket build (+dinv, z0 panels)
    hipMemsetAsync(gcursor, 0, NBUCK * 4, stream);
    bin_edges<<<(nE + 4095) / 4096, 256, 0, stream>>>(src, dst, gcursor, binned, nE);
    build_csr<<<nBk, 512, 0, stream>>>(binned, gcursor, rowptr, rowend, dinv, nbr,
                                       (const float4*)x, z0, nN);

    // 2. panel gathers: zB = bf16(D^-1 (A+I) z0); zC = bf16(D^-1/2 (A+I) zB)
    // grid = 8 XCD-slots x 782 -> 4 panels x 1564 chunks x 64 nodes
    const int gGrid = 8 * 782;
    gather_panel<2><<<gGrid, 256, 0, stream>>>(zB, z0, nbr, rowptr, rowend, dinv, nN);
    gather_panel<1><<<gGrid, 256, 0, stream>>>(zC, zB, nbr, rowptr, rowend, dinv, nN);

    // 3. persistent MFMA MLP + log_softmax
    const int nTiles = (nN + 63) / 64;
    mlp_mfma<<<392, 256, 0, stream>>>(out, zC, W1, b1, W2, b2, nN, nTiles);
}

// Round 13
// 170.383 us; speedup vs baseline: 1.4823x; 1.4823x over previous
//
#include <hip/hip_runtime.h>
#include <math.h>

#define N_NODES 100000
#define BSHIFT 9                 // 512-node buckets
#define NBUCK 256                // >= ceil(N/512)=196, pow2
#define CAPSHIFT 13              // 8192 slots per bucket (mean 6122, +26 sigma)
#define CAP (1 << CAPSHIFT)

typedef unsigned short bfu;
typedef unsigned int uint;
typedef __attribute__((ext_vector_type(8))) short short8v;   // 8 bf16 = 4 VGPRs
typedef __attribute__((ext_vector_type(4))) float f32x4;

__device__ __forceinline__ float bf2f(bfu u) {
    union { uint i; float f; } v; v.i = (uint)u << 16; return v.f;
}
__device__ __forceinline__ bfu f2bf(float f) {   // round-to-nearest-even
    union { float f_; uint i; } v; v.f_ = f;
    uint r = (v.i + 0x7FFFu + ((v.i >> 16) & 1u)) >> 16;
    return (bfu)r;
}
__device__ __forceinline__ float asf(uint u) {
    union { uint i; float f; } v; v.i = u; return v.f;
}

// ---------------------------------------------------------------- P1: bin edges by bucket
// Static bucket bases (b*CAP); per-chunk reservation via gcursor atomics.
__global__ __launch_bounds__(256) void bin_edges(const int* __restrict__ src,
                                                 const int* __restrict__ dst,
                                                 int* __restrict__ gcursor,
                                                 uint* __restrict__ binned, int nE) {
    __shared__ int h[NBUCK];
    __shared__ int base[NBUCK];
    int tid = threadIdx.x;
    int start = blockIdx.x * 4096;
    h[tid] = 0;
    __syncthreads();
    int bkt[16], rnk[16];
    #pragma unroll
    for (int u = 0; u < 16; ++u) {
        int e = start + u * 256 + tid;
        bkt[u] = -1;
        if (e < nE) {
            int b = dst[e] >> BSHIFT;
            bkt[u] = b;
            rnk[u] = atomicAdd(&h[b], 1);
        }
    }
    __syncthreads();
    base[tid] = h[tid] ? (tid << CAPSHIFT) + atomicAdd(&gcursor[tid], h[tid]) : 0;
    __syncthreads();
    #pragma unroll
    for (int u = 0; u < 16; ++u) {
        int e = start + u * 256 + tid;
        if (e < nE) {
            uint pk = ((uint)(dst[e] & 511) << 17) | (uint)src[e];  // src < 2^17
            binned[base[bkt[u]] + rnk[u]] = pk;
        }
    }
}

// ---------------------------------------------------------------- P2: per-bucket CSR build
// Gapped bucket-major nbr; rowptr/rowend per node; z0 = bf16(dinv*x) epilogue.
__global__ __launch_bounds__(512) void build_csr(
    const uint* __restrict__ binned, const int* __restrict__ gcursor,
    int* __restrict__ rowptr, int* __restrict__ rowend,
    float* __restrict__ dinv, int* __restrict__ nbr,
    const float4* __restrict__ x, ushort4* __restrict__ z0, int nN) {
    __shared__ int hist[512];
    __shared__ int cursor[512];
    int b = blockIdx.x, t = threadIdx.x;
    int n0 = b << BSHIFT;
    int nNodes = min(512, nN - n0);
    int base = b << CAPSHIFT;
    int cnt = gcursor[b];
    hist[t] = 0;
    __syncthreads();
    for (int i = t; i < cnt; i += 512)
        atomicAdd(&hist[binned[base + i] >> 17], 1);
    __syncthreads();
    int v = hist[t];
    #pragma unroll
    for (int off = 1; off < 512; off <<= 1) {
        int tv = (t >= off) ? hist[t - off] : 0;
        __syncthreads();
        hist[t] += tv;
        __syncthreads();
    }
    int excl = hist[t] - v;
    float dv = rsqrtf((float)v + 1.0f);           // +1 self loop
    if (t < nNodes) {
        rowptr[n0 + t] = base + excl;
        rowend[n0 + t] = base + excl + v;
        dinv[n0 + t] = dv;
    }
    cursor[t] = excl;
    __syncthreads();
    ((float*)hist)[t] = dv;                        // hist reused as dinv cache
    __syncthreads();
    for (int i = t; i < cnt; i += 512) {
        uint pk = binned[base + i];
        int ld = pk >> 17;
        int pos = atomicAdd(&cursor[ld], 1);
        nbr[base + pos] = (int)(pk & 0x1FFFFu);
    }
    // epilogue: z0 rows for this bucket, coalesced (standard [node][64] layout)
    const float4* xr = x + (size_t)n0 * 16;
    ushort4* zr = z0 + (size_t)n0 * 16;
    int totalF4 = nNodes * 16;
    for (int i = t; i < totalF4; i += 512) {
        float w = ((float*)hist)[i >> 4];
        float4 vv = xr[i];
        ushort4 o;
        o.x = f2bf(w * vv.x); o.y = f2bf(w * vv.y);
        o.z = f2bf(w * vv.z); o.w = f2bf(w * vv.w);
        zr[i] = o;
    }
}

// ---------------------------------------------------------------- hop1 gather, 8 rows/load
// wave = 1 node; 8 groups of 8 lanes; 128B row per group load (R12 lesson:
// never shrink the random-access quantum below 128B).
template<int PW>
__global__ __launch_bounds__(256, 8) void gather_hop8(
    bfu* __restrict__ out, const bfu* __restrict__ z,
    const int* __restrict__ nbr, const int* __restrict__ rowptr,
    const int* __restrict__ rowend, const float* __restrict__ dinv, int nN) {
    int node = blockIdx.x * 4 + (threadIdx.x >> 6);
    if (node >= nN) return;
    int lane = threadIdx.x & 63;
    int g = lane >> 3, k = lane & 7;
    int beg = rowptr[node], end = rowend[node];

    float acc[8];
    #pragma unroll
    for (int i = 0; i < 8; ++i) acc[i] = 0.f;

    auto rowload = [&](int s) -> uint4 {
        return reinterpret_cast<const uint4*>(z + (size_t)s * 64)[k];
    };
    auto accum = [&](uint4 v) {
        acc[0] += asf(v.x << 16); acc[1] += asf(v.x & 0xFFFF0000u);
        acc[2] += asf(v.y << 16); acc[3] += asf(v.y & 0xFFFF0000u);
        acc[4] += asf(v.z << 16); acc[5] += asf(v.z & 0xFFFF0000u);
        acc[6] += asf(v.w << 16); acc[7] += asf(v.w & 0xFFFF0000u);
    };

    if (g == 0)   // self loop
        accum(rowload(node));
    int j = beg + g;
    for (; j + 8 < end; j += 16) {
        int i0 = nbr[j], i1 = nbr[j + 8];
        uint4 v0 = rowload(i0);
        uint4 v1 = rowload(i1);
        accum(v0);
        accum(v1);
    }
    if (j < end)
        accum(rowload(nbr[j]));

    #pragma unroll
    for (int m = 8; m < 64; m <<= 1)
        #pragma unroll
        for (int i = 0; i < 8; ++i)
            acc[i] += __shfl_xor(acc[i], m);

    if (g == 0) {
        float di = dinv[node];
        float w = (PW == 2) ? di * di : di;
        uint4 o;
        o.x = ((uint)f2bf(acc[1] * w) << 16) | f2bf(acc[0] * w);
        o.y = ((uint)f2bf(acc[3] * w) << 16) | f2bf(acc[2] * w);
        o.z = ((uint)f2bf(acc[5] * w) << 16) | f2bf(acc[4] * w);
        o.w = ((uint)f2bf(acc[7] * w) << 16) | f2bf(acc[6] * w);
        reinterpret_cast<uint4*>(out + (size_t)node * 64)[k] = o;
    }
}

// ---------------------------------------------------------------- fused hop2 + MFMA MLP
// block = 256 threads = 64 nodes. Phase A: each wave gathers its 16 nodes'
// neighbor rows from zB (same 8-group/128B-row structure as gather_hop8),
// applies dinv, writes bf16 x into LDS. Phase B: stage1/stage2 MFMA + softmax.
// xh buffer recycled: x tile -> h tile (barrier-separated).
__global__ __launch_bounds__(256) void hop2_mlp(
    float* __restrict__ out, const bfu* __restrict__ zB,
    const int* __restrict__ nbr, const int* __restrict__ rowptr,
    const int* __restrict__ rowend, const float* __restrict__ dinv,
    const float* __restrict__ W1, const float* __restrict__ b1,
    const float* __restrict__ W2, const float* __restrict__ b2, int nN) {
    __shared__ short w1t[64 * 72];   // w1t[n][k] bf16
    __shared__ short w2t[48 * 72];   // w2t[n][k] bf16, n 40..47 = 0
    __shared__ short xh[64 * 72];    // gathered x tile, then h tile
    __shared__ float b1s[64];
    __shared__ float b2s[48];

    int tid = threadIdx.x;
    for (int i = tid; i < 64 * 64; i += 256) {
        int k = i >> 6, n = i & 63;
        w1t[n * 72 + k] = (short)f2bf(W1[i]);
    }
    for (int i = tid; i < 48 * 64; i += 256) {
        int k = i / 48, n = i % 48;
        w2t[n * 72 + k] = (short)(n < 40 ? f2bf(W2[k * 40 + n]) : 0);
    }
    if (tid < 64) b1s[tid] = b1[tid];
    if (tid >= 64 && tid < 112) b2s[tid - 64] = (tid - 64 < 40) ? b2[tid - 64] : 0.f;

    int wv = tid >> 6, l = tid & 63;
    int g = l >> 3, k = l & 7;

    auto rowload = [&](int s) -> uint4 {
        return reinterpret_cast<const uint4*>(zB + (size_t)s * 64)[k];
    };

    // ---- phase A: hop2 gather for this block's 64 nodes (16 per wave)
    int rowbase0 = blockIdx.x * 64 + wv * 16;
    for (int m = 0; m < 16; ++m) {
        int node = rowbase0 + m;                 // wave-uniform
        float acc[8];
        #pragma unroll
        for (int i = 0; i < 8; ++i) acc[i] = 0.f;
        if (node < nN) {
            int beg = rowptr[node], end = rowend[node];
            auto accum = [&](uint4 v) {
                acc[0] += asf(v.x << 16); acc[1] += asf(v.x & 0xFFFF0000u);
                acc[2] += asf(v.y << 16); acc[3] += asf(v.y & 0xFFFF0000u);
                acc[4] += asf(v.z << 16); acc[5] += asf(v.z & 0xFFFF0000u);
                acc[6] += asf(v.w << 16); acc[7] += asf(v.w & 0xFFFF0000u);
            };
            if (g == 0) accum(rowload(node));    // self loop
            for (int j = beg + g; j < end; j += 8)
                accum(rowload(nbr[j]));
            #pragma unroll
            for (int msk = 8; msk < 64; msk <<= 1)
                #pragma unroll
                for (int i = 0; i < 8; ++i)
                    acc[i] += __shfl_xor(acc[i], msk);
        }
        if (g == 0) {                            // lanes k=0..7 cover feats 0..63
            float w = (node < nN) ? dinv[node] : 0.f;
            short8v o;
            #pragma unroll
            for (int i = 0; i < 8; ++i) o[i] = (short)f2bf(acc[i] * w);
            *(short8v*)&xh[(wv * 16 + m) * 72 + k * 8] = o;
        }
    }
    __syncthreads();   // weights + x tile staged

    // ---- phase B: stage 1 (h = relu(x@W1+b1))
    int li = l & 15, kg = l >> 4;
    short8v a0 = *(const short8v*)&xh[(wv * 16 + li) * 72 + kg * 8];
    short8v a1 = *(const short8v*)&xh[(wv * 16 + li) * 72 + 32 + kg * 8];
    f32x4 acc1[4];
    #pragma unroll
    for (int nt = 0; nt < 4; ++nt) {
        f32x4 c = {0.f, 0.f, 0.f, 0.f};
        short8v b0 = *(const short8v*)&w1t[(nt * 16 + li) * 72 + kg * 8];
        short8v b1f = *(const short8v*)&w1t[(nt * 16 + li) * 72 + 32 + kg * 8];
        c = __builtin_amdgcn_mfma_f32_16x16x32_bf16(a0, b0, c, 0, 0, 0);
        c = __builtin_amdgcn_mfma_f32_16x16x32_bf16(a1, b1f, c, 0, 0, 0);
        acc1[nt] = c;
    }
    __syncthreads();   // all x reads done; xh becomes h
    #pragma unroll
    for (int nt = 0; nt < 4; ++nt) {
        float bb = b1s[nt * 16 + li];
        #pragma unroll
        for (int r = 0; r < 4; ++r) {
            float v = fmaxf(acc1[nt][r] + bb, 0.f);
            xh[(wv * 16 + kg * 4 + r) * 72 + nt * 16 + li] = (short)f2bf(v);
        }
    }
    __syncthreads();

    // stage 2: logits = h@W2+b2 (N=48, cols 40..47 zero)
    const short8v* hp = (const short8v*)&xh[(wv * 16 + li) * 72];
    short8v ha0 = hp[kg];
    short8v ha1 = hp[kg + 4];
    f32x4 acc2[3];
    #pragma unroll
    for (int nt = 0; nt < 3; ++nt) {
        f32x4 c = {0.f, 0.f, 0.f, 0.f};
        short8v b0 = *(const short8v*)&w2t[(nt * 16 + li) * 72 + kg * 8];
        short8v b1f = *(const short8v*)&w2t[(nt * 16 + li) * 72 + 32 + kg * 8];
        c = __builtin_amdgcn_mfma_f32_16x16x32_bf16(ha0, b0, c, 0, 0, 0);
        c = __builtin_amdgcn_mfma_f32_16x16x32_bf16(ha1, b1f, c, 0, 0, 0);
        acc2[nt] = c;
    }

    float lg[3][4];
    #pragma unroll
    for (int nt = 0; nt < 3; ++nt) {
        float bb = b2s[nt * 16 + li];
        #pragma unroll
        for (int r = 0; r < 4; ++r) lg[nt][r] = acc2[nt][r] + bb;
    }
    bool v2 = (li < 8);   // tile 2 valid cols 32..39
    float mx[4], sm[4];
    #pragma unroll
    for (int r = 0; r < 4; ++r) {
        float m = fmaxf(lg[0][r], lg[1][r]);
        if (v2) m = fmaxf(m, lg[2][r]);
        mx[r] = m;
    }
    #pragma unroll
    for (int off = 1; off < 16; off <<= 1)
        #pragma unroll
        for (int r = 0; r < 4; ++r)
            mx[r] = fmaxf(mx[r], __shfl_xor(mx[r], off));
    #pragma unroll
    for (int r = 0; r < 4; ++r) {
        float s = expf(lg[0][r] - mx[r]) + expf(lg[1][r] - mx[r]);
        if (v2) s += expf(lg[2][r] - mx[r]);
        sm[r] = s;
    }
    #pragma unroll
    for (int off = 1; off < 16; off <<= 1)
        #pragma unroll
        for (int r = 0; r < 4; ++r)
            sm[r] += __shfl_xor(sm[r], off);

    int nb2 = blockIdx.x * 64 + wv * 16 + kg * 4;
    #pragma unroll
    for (int r = 0; r < 4; ++r) {
        int nd = nb2 + r;
        if (nd < nN) {
            float lse = mx[r] + logf(sm[r]);
            out[(size_t)nd * 40 + li]      = lg[0][r] - lse;
            out[(size_t)nd * 40 + 16 + li] = lg[1][r] - lse;
            if (v2) out[(size_t)nd * 40 + 32 + li] = lg[2][r] - lse;
        }
    }
}

extern "C" void kernel_launch(void* const* d_in, const int* in_sizes, int n_in,
                              void* d_out, int out_size, void* d_ws, size_t ws_size,
                              hipStream_t stream) {
    const float* x   = (const float*)d_in[0];
    const int* eidx  = (const int*)d_in[1];
    const float* W1  = (const float*)d_in[2];
    const float* b1  = (const float*)d_in[3];
    const float* W2  = (const float*)d_in[4];
    const float* b2  = (const float*)d_in[5];
    float* out = (float*)d_out;

    const int nN = N_NODES;
    const int nE = in_sizes[1] / 2;  // edge_index is [2, E]
    const int* src = eidx;
    const int* dst = eidx + nE;
    const int nBk = (nN + 511) >> BSHIFT;   // 196 buckets

    // ---- workspace layout (256B aligned)
    char* ws = (char*)d_ws;
    size_t off = 0;
    auto alloc = [&](size_t bytes) {
        char* p = ws + off;
        off += (bytes + 255) & ~(size_t)255;
        return p;
    };
    float* dinv    = (float*)alloc((size_t)nN * 4);
    int*   gcursor = (int*)  alloc(NBUCK * 4);
    int*   rowptr  = (int*)  alloc((size_t)nN * 4);
    int*   rowend  = (int*)  alloc((size_t)nN * 4);
    uint*  binned  = (uint*) alloc((size_t)NBUCK * CAP * 4);   // 8 MB, gapped
    int*   nbr     = (int*)  alloc((size_t)NBUCK * CAP * 4);   // 8 MB, gapped
    bfu*   z0      = (bfu*)  alloc((size_t)nN * 64 * 2);
    bfu*   zB      = (bfu*)  alloc((size_t)nN * 64 * 2);

    // 1. CSR build: bin (static bucket bases) -> per-bucket build (+dinv, z0)
    hipMemsetAsync(gcursor, 0, NBUCK * 4, stream);
    bin_edges<<<(nE + 4095) / 4096, 256, 0, stream>>>(src, dst, gcursor, binned, nE);
    build_csr<<<nBk, 512, 0, stream>>>(binned, gcursor, rowptr, rowend, dinv, nbr,
                                       (const float4*)x, (ushort4*)z0, nN);

    // 2. hop1: zB = bf16(D^-1 (A+I) z0)
    const int gBlocks = (nN + 3) / 4;
    gather_hop8<2><<<gBlocks, 256, 0, stream>>>(zB, z0, nbr, rowptr, rowend, dinv, nN);

    // 3. fused hop2 + MFMA MLP + log_softmax
    hop2_mlp<<<(nN + 63) / 64, 256, 0, stream>>>(out, zB, nbr, rowptr, rowend, dinv,
                                                 W1, b1, W2, b2, nN);
}

// Round 14
// 142.867 us; speedup vs baseline: 1.7679x; 1.1926x over previous
//
#include <hip/hip_runtime.h>
#include <math.h>

#define N_NODES 100000
#define BSHIFT 9                 // 512-node buckets
#define NBUCK 256                // >= ceil(N/512)=196, pow2
#define CAPSHIFT 13              // 8192 slots per bucket (mean 6122, +26 sigma)
#define CAP (1 << CAPSHIFT)

typedef unsigned short bfu;
typedef unsigned int uint;
typedef __attribute__((ext_vector_type(8))) short short8v;   // 8 bf16 = 4 VGPRs
typedef __attribute__((ext_vector_type(4))) float f32x4;

__device__ __forceinline__ float bf2f(bfu u) {
    union { uint i; float f; } v; v.i = (uint)u << 16; return v.f;
}
__device__ __forceinline__ bfu f2bf(float f) {   // round-to-nearest-even
    union { float f_; uint i; } v; v.f_ = f;
    uint r = (v.i + 0x7FFFu + ((v.i >> 16) & 1u)) >> 16;
    return (bfu)r;
}
__device__ __forceinline__ float asf(uint u) {
    union { uint i; float f; } v; v.i = u; return v.f;
}

// ---------------------------------------------------------------- P1: bin edges by bucket
// Static bucket bases (b*CAP). Packed word cached in registers: dst/src read ONCE.
__global__ __launch_bounds__(256) void bin_edges(const int* __restrict__ src,
                                                 const int* __restrict__ dst,
                                                 int* __restrict__ gcursor,
                                                 uint* __restrict__ binned, int nE) {
    __shared__ int h[NBUCK];
    __shared__ int base[NBUCK];
    int tid = threadIdx.x;
    int start = blockIdx.x * 4096;
    h[tid] = 0;
    __syncthreads();
    int bkt[16], rnk[16];
    uint pk[16];
    #pragma unroll
    for (int u = 0; u < 16; ++u) {
        int e = start + u * 256 + tid;
        bkt[u] = -1;
        if (e < nE) {
            int d = dst[e];
            int b = d >> BSHIFT;
            bkt[u] = b;
            pk[u] = ((uint)(d & 511) << 17) | (uint)src[e];   // src < 2^17
            rnk[u] = atomicAdd(&h[b], 1);
        }
    }
    __syncthreads();
    base[tid] = h[tid] ? (tid << CAPSHIFT) + atomicAdd(&gcursor[tid], h[tid]) : 0;
    __syncthreads();
    #pragma unroll
    for (int u = 0; u < 16; ++u) {
        if (bkt[u] >= 0)
            binned[base[bkt[u]] + rnk[u]] = pk[u];
    }
}

// ---------------------------------------------------------------- P2: per-bucket CSR build
// Bucket's binned words staged once in LDS (32KB); hist/scan/scatter from LDS.
// Outputs: rowptr/rowend, dinv, nbr (gapped), z0 = bf16(dinv*x).
__global__ __launch_bounds__(512) void build_csr(
    const uint* __restrict__ binned, const int* __restrict__ gcursor,
    int* __restrict__ rowptr, int* __restrict__ rowend,
    float* __restrict__ dinv, int* __restrict__ nbr,
    const float4* __restrict__ x, ushort4* __restrict__ z0, int nN) {
    __shared__ uint sbin[CAP];      // 32 KB
    __shared__ int hist[512];
    __shared__ int cursor[512];
    int b = blockIdx.x, t = threadIdx.x;
    int n0 = b << BSHIFT;
    int nNodes = min(512, nN - n0);
    int base = b << CAPSHIFT;
    int cnt = gcursor[b];
    hist[t] = 0;
    __syncthreads();
    for (int i = t; i < cnt; i += 512) {        // single coalesced global read
        uint pk = binned[base + i];
        sbin[i] = pk;
        atomicAdd(&hist[pk >> 17], 1);
    }
    __syncthreads();
    int v = hist[t];
    #pragma unroll
    for (int off = 1; off < 512; off <<= 1) {
        int tv = (t >= off) ? hist[t - off] : 0;
        __syncthreads();
        hist[t] += tv;
        __syncthreads();
    }
    int excl = hist[t] - v;
    float dv = rsqrtf((float)v + 1.0f);           // +1 self loop
    if (t < nNodes) {
        rowptr[n0 + t] = base + excl;
        rowend[n0 + t] = base + excl + v;
        dinv[n0 + t] = dv;
    }
    cursor[t] = excl;
    __syncthreads();
    ((float*)hist)[t] = dv;                        // hist reused as dinv cache
    __syncthreads();
    for (int i = t; i < cnt; i += 512) {           // scatter from LDS
        uint pk = sbin[i];
        int ld = pk >> 17;
        int pos = atomicAdd(&cursor[ld], 1);
        nbr[base + pos] = (int)(pk & 0x1FFFFu);
    }
    // epilogue: z0 rows for this bucket, coalesced
    const float4* xr = x + (size_t)n0 * 16;
    ushort4* zr = z0 + (size_t)n0 * 16;
    int totalF4 = nNodes * 16;
    for (int i = t; i < totalF4; i += 512) {
        float w = ((float*)hist)[i >> 4];
        float4 vv = xr[i];
        ushort4 o;
        o.x = f2bf(w * vv.x); o.y = f2bf(w * vv.y);
        o.z = f2bf(w * vv.z); o.w = f2bf(w * vv.w);
        zr[i] = o;
    }
}

// ---------------------------------------------------------------- gather hop, 8 rows/load
// wave = 1 node; 8 groups of 8 lanes; 128B row per group load (R12 lesson:
// never shrink the random-access quantum below 128B; R13 lesson: keep
// 1 node/wave TLP, don't serialize nodes within a wave).
template<int PW>
__global__ __launch_bounds__(256, 8) void gather_hop8(
    bfu* __restrict__ out, const bfu* __restrict__ z,
    const int* __restrict__ nbr, const int* __restrict__ rowptr,
    const int* __restrict__ rowend, const float* __restrict__ dinv, int nN) {
    int node = blockIdx.x * 4 + (threadIdx.x >> 6);
    if (node >= nN) return;
    int lane = threadIdx.x & 63;
    int g = lane >> 3, k = lane & 7;
    int beg = rowptr[node], end = rowend[node];

    float acc[8];
    #pragma unroll
    for (int i = 0; i < 8; ++i) acc[i] = 0.f;

    auto rowload = [&](int s) -> uint4 {
        return reinterpret_cast<const uint4*>(z + (size_t)s * 64)[k];
    };
    auto accum = [&](uint4 v) {
        acc[0] += asf(v.x << 16); acc[1] += asf(v.x & 0xFFFF0000u);
        acc[2] += asf(v.y << 16); acc[3] += asf(v.y & 0xFFFF0000u);
        acc[4] += asf(v.z << 16); acc[5] += asf(v.z & 0xFFFF0000u);
        acc[6] += asf(v.w << 16); acc[7] += asf(v.w & 0xFFFF0000u);
    };

    if (g == 0)   // self loop
        accum(rowload(node));
    int j = beg + g;
    for (; j + 8 < end; j += 16) {
        int i0 = nbr[j], i1 = nbr[j + 8];
        uint4 v0 = rowload(i0);
        uint4 v1 = rowload(i1);
        accum(v0);
        accum(v1);
    }
    if (j < end)
        accum(rowload(nbr[j]));

    #pragma unroll
    for (int m = 8; m < 64; m <<= 1)
        #pragma unroll
        for (int i = 0; i < 8; ++i)
            acc[i] += __shfl_xor(acc[i], m);

    if (g == 0) {
        float di = dinv[node];
        float w = (PW == 2) ? di * di : di;
        uint4 o;
        o.x = ((uint)f2bf(acc[1] * w) << 16) | f2bf(acc[0] * w);
        o.y = ((uint)f2bf(acc[3] * w) << 16) | f2bf(acc[2] * w);
        o.z = ((uint)f2bf(acc[5] * w) << 16) | f2bf(acc[4] * w);
        o.w = ((uint)f2bf(acc[7] * w) << 16) | f2bf(acc[6] * w);
        reinterpret_cast<uint4*>(out + (size_t)node * 64)[k] = o;
    }
}

// ---------------------------------------------------------------- MFMA MLP + log_softmax
// PERSISTENT: each block stages weights ONCE, then grid-strides over 64-node tiles.
__global__ __launch_bounds__(256) void mlp_mfma(
    float* __restrict__ out, const bfu* __restrict__ zC,
    const float* __restrict__ W1, const float* __restrict__ b1,
    const float* __restrict__ W2, const float* __restrict__ b2,
    int nN, int nTiles) {
    __shared__ short w1t[64 * 72];   // w1t[n][k] bf16
    __shared__ short w2t[48 * 72];   // w2t[n][k] bf16, n 40..47 = 0
    __shared__ short hlds[64 * 72];  // h[node][hid] bf16
    __shared__ float b1s[64];
    __shared__ float b2s[48];

    int tid = threadIdx.x;
    for (int i = tid; i < 64 * 64; i += 256) {
        int k = i >> 6, n = i & 63;
        w1t[n * 72 + k] = (short)f2bf(W1[i]);
    }
    for (int i = tid; i < 48 * 64; i += 256) {
        int k = i / 48, n = i % 48;
        w2t[n * 72 + k] = (short)(n < 40 ? f2bf(W2[k * 40 + n]) : 0);
    }
    if (tid < 64) b1s[tid] = b1[tid];
    if (tid >= 64 && tid < 112) b2s[tid - 64] = (tid - 64 < 40) ? b2[tid - 64] : 0.f;

    int wv = tid >> 6, l = tid & 63;
    int li = l & 15, kg = l >> 4;

    for (int tile = blockIdx.x; tile < nTiles; tile += gridDim.x) {
        int nodebase = tile * 64 + wv * 16;
        int nclamp = min(nodebase + li, nN - 1);

        const short8v* zr = (const short8v*)(zC + (size_t)nclamp * 64);
        short8v a0 = zr[kg];
        short8v a1 = zr[kg + 4];
        __syncthreads();   // weights staged (iter 0); hlds readers done (iter >0)

        f32x4 acc[4];
        #pragma unroll
        for (int nt = 0; nt < 4; ++nt) {
            f32x4 c = {0.f, 0.f, 0.f, 0.f};
            short8v b0 = *(const short8v*)&w1t[(nt * 16 + li) * 72 + kg * 8];
            short8v b1f = *(const short8v*)&w1t[(nt * 16 + li) * 72 + 32 + kg * 8];
            c = __builtin_amdgcn_mfma_f32_16x16x32_bf16(a0, b0, c, 0, 0, 0);
            c = __builtin_amdgcn_mfma_f32_16x16x32_bf16(a1, b1f, c, 0, 0, 0);
            acc[nt] = c;
        }
        #pragma unroll
        for (int nt = 0; nt < 4; ++nt) {
            float bb = b1s[nt * 16 + li];
            #pragma unroll
            for (int r = 0; r < 4; ++r) {
                float v = fmaxf(acc[nt][r] + bb, 0.f);
                hlds[(wv * 16 + kg * 4 + r) * 72 + nt * 16 + li] = (short)f2bf(v);
            }
        }
        __syncthreads();

        const short8v* hp = (const short8v*)&hlds[(wv * 16 + li) * 72];
        short8v ha0 = hp[kg];
        short8v ha1 = hp[kg + 4];
        f32x4 acc2[3];
        #pragma unroll
        for (int nt = 0; nt < 3; ++nt) {
            f32x4 c = {0.f, 0.f, 0.f, 0.f};
            short8v b0 = *(const short8v*)&w2t[(nt * 16 + li) * 72 + kg * 8];
            short8v b1f = *(const short8v*)&w2t[(nt * 16 + li) * 72 + 32 + kg * 8];
            c = __builtin_amdgcn_mfma_f32_16x16x32_bf16(ha0, b0, c, 0, 0, 0);
            c = __builtin_amdgcn_mfma_f32_16x16x32_bf16(ha1, b1f, c, 0, 0, 0);
            acc2[nt] = c;
        }

        float lg[3][4];
        #pragma unroll
        for (int nt = 0; nt < 3; ++nt) {
            float bb = b2s[nt * 16 + li];
            #pragma unroll
            for (int r = 0; r < 4; ++r) lg[nt][r] = acc2[nt][r] + bb;
        }
        bool v2 = (li < 8);   // tile 2 valid cols 32..39
        float mx[4], sm[4];
        #pragma unroll
        for (int r = 0; r < 4; ++r) {
            float m = fmaxf(lg[0][r], lg[1][r]);
            if (v2) m = fmaxf(m, lg[2][r]);
            mx[r] = m;
        }
        #pragma unroll
        for (int off = 1; off < 16; off <<= 1)
            #pragma unroll
            for (int r = 0; r < 4; ++r)
                mx[r] = fmaxf(mx[r], __shfl_xor(mx[r], off));
        #pragma unroll
        for (int r = 0; r < 4; ++r) {
            float s = expf(lg[0][r] - mx[r]) + expf(lg[1][r] - mx[r]);
            if (v2) s += expf(lg[2][r] - mx[r]);
            sm[r] = s;
        }
        #pragma unroll
        for (int off = 1; off < 16; off <<= 1)
            #pragma unroll
            for (int r = 0; r < 4; ++r)
                sm[r] += __shfl_xor(sm[r], off);

        int nb2 = nodebase + kg * 4;
        #pragma unroll
        for (int r = 0; r < 4; ++r) {
            int nd = nb2 + r;
            if (nd < nN) {
                float lse = mx[r] + logf(sm[r]);
                out[(size_t)nd * 40 + li]      = lg[0][r] - lse;
                out[(size_t)nd * 40 + 16 + li] = lg[1][r] - lse;
                if (v2) out[(size_t)nd * 40 + 32 + li] = lg[2][r] - lse;
            }
        }
    }
}

extern "C" void kernel_launch(void* const* d_in, const int* in_sizes, int n_in,
                              void* d_out, int out_size, void* d_ws, size_t ws_size,
                              hipStream_t stream) {
    const float* x   = (const float*)d_in[0];
    const int* eidx  = (const int*)d_in[1];
    const float* W1  = (const float*)d_in[2];
    const float* b1  = (const float*)d_in[3];
    const float* W2  = (const float*)d_in[4];
    const float* b2  = (const float*)d_in[5];
    float* out = (float*)d_out;

    const int nN = N_NODES;
    const int nE = in_sizes[1] / 2;  // edge_index is [2, E]
    const int* src = eidx;
    const int* dst = eidx + nE;
    const int nBk = (nN + 511) >> BSHIFT;   // 196 buckets

    // ---- workspace layout (256B aligned)
    char* ws = (char*)d_ws;
    size_t off = 0;
    auto alloc = [&](size_t bytes) {
        char* p = ws + off;
        off += (bytes + 255) & ~(size_t)255;
        return p;
    };
    float* dinv    = (float*)alloc((size_t)nN * 4);
    int*   gcursor = (int*)  alloc(NBUCK * 4);
    int*   rowptr  = (int*)  alloc((size_t)nN * 4);
    int*   rowend  = (int*)  alloc((size_t)nN * 4);
    uint*  binned  = (uint*) alloc((size_t)NBUCK * CAP * 4);   // 8 MB, gapped
    int*   nbr     = (int*)  alloc((size_t)NBUCK * CAP * 4);   // 8 MB, gapped
    bfu*   z0      = (bfu*)  alloc((size_t)nN * 64 * 2);
    bfu*   zB      = (bfu*)  alloc((size_t)nN * 64 * 2);
    bfu*   zC      = (bfu*)  alloc((size_t)nN * 64 * 2);

    // 1. CSR build: bin (static bucket bases) -> per-bucket build (+dinv, z0)
    hipMemsetAsync(gcursor, 0, NBUCK * 4, stream);
    bin_edges<<<(nE + 4095) / 4096, 256, 0, stream>>>(src, dst, gcursor, binned, nE);
    build_csr<<<nBk, 512, 0, stream>>>(binned, gcursor, rowptr, rowend, dinv, nbr,
                                       (const float4*)x, (ushort4*)z0, nN);

    // 2. zB = bf16(D^-1 (A+I) z0); zC = bf16(D^-1/2 (A+I) zB)
    const int gBlocks = (nN + 3) / 4;
    gather_hop8<2><<<gBlocks, 256, 0, stream>>>(zB, z0, nbr, rowptr, rowend, dinv, nN);
    gather_hop8<1><<<gBlocks, 256, 0, stream>>>(zC, zB, nbr, rowptr, rowend, dinv, nN);

    // 3. persistent MFMA MLP + log_softmax
    const int nTiles = (nN + 63) / 64;
    mlp_mfma<<<392, 256, 0, stream>>>(out, zC, W1, b1, W2, b2, nN, nTiles);
}